// Round 3
// baseline (27.258 us; speedup 1.0000x reference)
//
#include <hip/hip_runtime.h>

// HardUpsampling: seqs [N=16, T=2048, M=256] f32, durations [N, T] i32 in [0,4)
// out = concat( upsampled [N, L, M] f32 , lens [N] (written as f32) )
// L = (out_size - N) / (N*M), known host-side from out_size.
//
// Round 3: single fused kernel.
//  - Each wave owns 8 consecutive positions [p, p+8).
//  - Wave recomputes prefix(p) and len itself: coalesced int4 reduction over
//    the row's 8KB durations (L1-hot), packed (prefix | len<<16) so ONE
//    6-step shfl_xor chain reduces both. No cross-wave sync, no 2nd kernel.
//  - Preloads up to 8 seqs rows (8 independent 16B/lane loads in flight),
//    then scatters each to its d consecutive output rows; pads [len, max_len)
//    with zeros; wave p==0 writes lens[n]. Every output row written exactly once.

#define N_ROWS 16
#define T_LEN  2048
#define M_DIM  256
#define M_VEC  (M_DIM / 4)   // 64 float4 per row
#define W_TOK  8             // tokens per wave

__global__ __launch_bounds__(256) void fused_upsample_kernel(
    const float4* __restrict__ seqs4, const int* __restrict__ dur,
    float4* __restrict__ out4, float* __restrict__ lens_out, int max_len) {
  const int lane = threadIdx.x & 63;
  const int wave = threadIdx.x >> 6;
  const int n = blockIdx.y;
  const int p = (blockIdx.x * 4 + wave) * W_TOK;   // this wave's base position

  const int* __restrict__ drow = dur + n * T_LEN;

  // ---- per-wave reduction: prefix(p) in lo16, total len in hi16 ----
  int pack = 0;
  for (int off = lane * 4; off < T_LEN; off += 256) {
    const int4 v = *(const int4*)(drow + off);     // coalesced, L1-hot (8KB/row)
    const int s = v.x + v.y + v.z + v.w;
    pack += (s << 16) + ((off < p) ? s : 0);       // off,p mult of 4 -> clean split
  }
#pragma unroll
  for (int d = 1; d < 64; d <<= 1) pack += __shfl_xor(pack, d, 64);
  const int prefix = pack & 0xFFFF;                // cum before p
  const int len = pack >> 16;                      // row total (<= 6144)

  if (p == 0 && lane == 0) lens_out[n] = (float)len;

  // ---- this wave's 8 durations + exclusive scan ----
  int dv = 0;
  if (lane < W_TOK && p + lane < T_LEN) dv = drow[p + lane];
  int dk[W_TOK], st[W_TOK];
  int run = prefix;
#pragma unroll
  for (int k = 0; k < W_TOK; ++k) {
    dk[k] = __shfl(dv, k, 64);
    st[k] = run;
    run += dk[k];
  }

  const float4* __restrict__ srow = seqs4 + (size_t)n * T_LEN * M_VEC + lane;
  float4* __restrict__ orow = out4 + (size_t)n * max_len * M_VEC + lane;

  // ---- preload rows (8 independent loads in flight) ----
  float4 v[W_TOK];
#pragma unroll
  for (int k = 0; k < W_TOK; ++k) {
    v[k] = make_float4(0.f, 0.f, 0.f, 0.f);
    if (p + k < T_LEN && dk[k] > 0) v[k] = srow[(size_t)(p + k) * M_VEC];
  }

  // ---- scatter: rows [st[k], st[k]+dk[k]) , all < len, exactly once ----
#pragma unroll
  for (int k = 0; k < W_TOK; ++k) {
    if (p + k < T_LEN) {
      for (int i = st[k]; i < st[k] + dk[k]; ++i)
        orow[(size_t)i * M_VEC] = v[k];
    }
  }

  // ---- padding: output rows [len, max_len) in this wave's range ----
#pragma unroll
  for (int k = 0; k < W_TOK; ++k) {
    const int i = p + k;
    if (i >= len && i < max_len)
      orow[(size_t)i * M_VEC] = make_float4(0.f, 0.f, 0.f, 0.f);
  }
}

extern "C" void kernel_launch(void* const* d_in, const int* in_sizes, int n_in,
                              void* d_out, int out_size, void* d_ws, size_t ws_size,
                              hipStream_t stream) {
  const float* seqs = (const float*)d_in[0];       // [16, 2048, 256] f32
  const int* durations = (const int*)d_in[1];      // [16, 2048] i32
  float* out = (float*)d_out;

  const int N = N_ROWS;
  const int M = M_DIM;
  const int max_len = (out_size - N) / (N * M);    // padded output length L

  float* lens_out = out + (size_t)N * max_len * M; // lens chunk (as f32 values)

  const int span = (max_len > T_LEN) ? max_len : T_LEN;
  dim3 grid((span + 4 * W_TOK - 1) / (4 * W_TOK), N);
  fused_upsample_kernel<<<grid, dim3(256), 0, stream>>>(
      (const float4*)seqs, durations, (float4*)out, out ? lens_out : lens_out,
      max_len);
}